// Round 1
// baseline (962.046 us; speedup 1.0000x reference)
//
#include <hip/hip_runtime.h>
#include <cstddef>
#include <cstdint>

typedef __attribute__((ext_vector_type(8))) _Float16 half8;
typedef __attribute__((ext_vector_type(4))) float f32x4;
typedef _Float16 half_t;

#define NS 16
#define NN 32
#define NPIX 4096

// ---------------- workspace layout (bytes) ----------------
// h1  : f16 [n][s][pix][32]  = 134217728
// h2  : f16 [n][s][pix][64]  = 268435456
// wt1 : f32 [s][3][9][32]    = 55296
// wt2 : f16 [s][9][64][32]   = 589824
// wt3 : f16 [s][9][64][64]   = 1179648
// sums: f32 [512*2 | 1024*2 | 1024*2] = 20480
// prm : f32 [a1 512][b1 512][a2 1024][b2 1024][a3 1024][b3 1024] = 20480
static const size_t OFF_H1 = 0;
static const size_t OFF_H2 = 134217728ull;
static const size_t OFF_WT1 = OFF_H2 + 268435456ull;
static const size_t OFF_WT2 = OFF_WT1 + 55296ull;
static const size_t OFF_WT3 = OFF_WT2 + 589824ull;
static const size_t OFF_SUMS = OFF_WT3 + 1179648ull;
static const size_t OFF_PRM = OFF_SUMS + 20480ull;
// total ~404.5 MB; assumes ws_size >= OFF_PRM + 20480

// -------- weight re-layout: oc-contiguous (conv1) / ic-contiguous (conv2/3) --------
__global__ __launch_bounds__(256) void transform_k(
    const float* __restrict__ w1, const float* __restrict__ w2,
    const float* __restrict__ w3, float* __restrict__ wt1,
    half_t* __restrict__ wt2, half_t* __restrict__ wt3)
{
    int idx = blockIdx.x * 256 + threadIdx.x;
    if (idx < 13824) {
        // wt1[s][ic][tap][oc] <- w1[(s*32+oc)][ic][tap]
        int o = idx & 31, tap = (idx >> 5) % 9, ic = (idx / 288) % 3, s = idx / 864;
        wt1[idx] = w1[((s * 32 + o) * 3 + ic) * 9 + tap];
    } else if (idx < 13824 + 294912) {
        // wt2[s][tap][oc][ic32] <- w2[(s*64+oc)][ic][tap]
        int t = idx - 13824;
        int ic = t & 31, oc = (t >> 5) & 63, tap = (t >> 11) % 9, s = t / 18432;
        wt2[t] = (half_t)w2[((s * 64 + oc) * 32 + ic) * 9 + tap];
    } else {
        // wt3[s][tap][oc][ic64] <- w3[(s*64+oc)][ic][tap]
        int t = idx - (13824 + 294912);
        int ic = t & 63, oc = (t >> 6) & 63, tap = (t >> 12) % 9, s = t / 36864;
        wt3[t] = (half_t)w3[((s * 64 + oc) * 64 + ic) * 9 + tap];
    }
}

// -------- conv1: 3->32 per seed, fp32 vector math, writes h1 (f16 pre-BN) + stats --------
__global__ __launch_bounds__(256) void conv1_k(
    const float* __restrict__ x, const float* __restrict__ wt1,
    const float* __restrict__ b1, half_t* __restrict__ h1,
    float* __restrict__ sums1)
{
    __shared__ float smem[8512];          // xt(972) / bounce(256*33) overlap, statsl @8448
    float* xt = smem;
    float* bounce = smem;
    float* statsl = smem + 8448;          // [32 oc][2]
    const int tile = blockIdx.x, s = blockIdx.y, n = blockIdx.z;
    const int tx = tile & 3, ty = tile >> 2, tid = threadIdx.x;

    for (int i = tid; i < 972; i += 256) {
        int ic = i / 324, rem = i - ic * 324;
        int py = rem / 18, px = rem - py * 18;
        int gy = ty * 16 + py - 1, gx = tx * 16 + px - 1;
        float v = 0.f;
        if ((unsigned)gy < 64u && (unsigned)gx < 64u)
            v = x[(size_t)(((s * NN + n) * 3 + ic) * 64 + gy) * 64 + gx];
        xt[i] = v;
    }
    if (tid < 64) statsl[tid] = 0.f;
    __syncthreads();

    const int px = tid & 15, py = tid >> 4;
    float acc[32];
#pragma unroll
    for (int o = 0; o < 32; ++o) acc[o] = 0.f;
#pragma unroll
    for (int ic = 0; ic < 3; ++ic)
#pragma unroll
        for (int ky = 0; ky < 3; ++ky)
#pragma unroll
            for (int kx = 0; kx < 3; ++kx) {
                float v = xt[ic * 324 + (py + ky) * 18 + px + kx];
                const float* wp = wt1 + ((s * 3 + ic) * 9 + ky * 3 + kx) * 32; // block-uniform -> s_load
#pragma unroll
                for (int o = 0; o < 32; ++o) acc[o] = fmaf(wp[o], v, acc[o]);
            }
    const float* bp = b1 + s * 32;
#pragma unroll
    for (int o = 0; o < 32; ++o) acc[o] += bp[o];

    const int gp = (ty * 16 + py) * 64 + tx * 16 + px;
    half8* dst = (half8*)(h1 + ((size_t)((n * NS + s) * NPIX + gp)) * 32);
#pragma unroll
    for (int k = 0; k < 4; ++k) {
        half8 v8;
#pragma unroll
        for (int j = 0; j < 8; ++j) v8[j] = (half_t)acc[k * 8 + j];
        dst[k] = v8;
    }
    __syncthreads();                      // xt reads done -> reuse as bounce
#pragma unroll
    for (int o = 0; o < 32; ++o) bounce[tid * 33 + o] = acc[o];
    __syncthreads();
    {
        const int oc = tid & 31, grp = tid >> 5;
        float s1 = 0.f, s2 = 0.f;
#pragma unroll 4
        for (int j = 0; j < 32; ++j) {
            float v = bounce[(grp * 32 + j) * 33 + oc];
            s1 += v; s2 += v * v;
        }
        atomicAdd(&statsl[oc * 2], s1);
        atomicAdd(&statsl[oc * 2 + 1], s2);
    }
    __syncthreads();
    if (tid < 64)
        atomicAdd(&sums1[(s * 32 + (tid >> 1)) * 2 + (tid & 1)], statsl[tid]);
}

// -------- sums -> (scale, shift) --------
__global__ void bnparam_k(const float* __restrict__ sums, const float* __restrict__ g,
                          const float* __restrict__ be, float* __restrict__ a,
                          float* __restrict__ b, int C)
{
    int ch = blockIdx.x * 256 + threadIdx.x;
    if (ch >= C) return;
    const float inv = 1.f / 131072.f;     // N*H*W = 32*64*64
    float mean = sums[ch * 2] * inv;
    float var = sums[ch * 2 + 1] * inv - mean * mean;
    float sc = g[ch] * rsqrtf(var + 1e-5f);
    a[ch] = sc;
    b[ch] = be[ch] - mean * sc;
}

// -------- conv2: 32->64 per seed, MFMA f16, BN1+ReLU folded into staging --------
__global__ __launch_bounds__(256) void conv2_k(
    const half_t* __restrict__ h1, const half_t* __restrict__ wt2,
    const float* __restrict__ b2, const float* __restrict__ a1,
    const float* __restrict__ b1p, half_t* __restrict__ h2,
    float* __restrict__ sums2)
{
    __shared__ __align__(16) char smem[33536]; // in tile (324*80) / out bounce (32768) overlap
    half_t* out_lds = (half_t*)smem;
    float* pa = (float*)(smem + 32768);
    float* pb = pa + 32;
    float* statsl = (float*)(smem + 33024); // [64 oc][2]

    const int tile = blockIdx.x, s = blockIdx.y, n = blockIdx.z;
    const int tx = tile & 3, ty = tile >> 2, tid = threadIdx.x;

    if (tid < 32) { pa[tid] = a1[s * 32 + tid]; pb[tid] = b1p[s * 32 + tid]; }
    if (tid >= 128) statsl[tid - 128] = 0.f;
    __syncthreads();

    // stage 18x18x32 tile (LDS pixel stride 80 B), apply BN1+ReLU, zero pad
    for (int i = tid; i < 1296; i += 256) {
        int p = i >> 2, cc = i & 3;
        int hy = p / 18, hx = p - hy * 18;
        int gy = ty * 16 + hy - 1, gx = tx * 16 + hx - 1;
        half8 v = {};
        if ((unsigned)gy < 64u && (unsigned)gx < 64u) {
            v = *(const half8*)(h1 + ((size_t)((n * NS + s) * NPIX + gy * 64 + gx)) * 32 + cc * 8);
#pragma unroll
            for (int j = 0; j < 8; ++j) {
                float f = fmaf(pa[cc * 8 + j], (float)v[j], pb[cc * 8 + j]);
                v[j] = (half_t)fmaxf(f, 0.f);
            }
        }
        *(half8*)(smem + p * 80 + cc * 16) = v;
    }
    __syncthreads();

    const int l = tid & 63, wv = tid >> 6, l15 = l & 15, g = l >> 4;
    f32x4 acc[4][4];
#pragma unroll
    for (int mt = 0; mt < 4; ++mt)
#pragma unroll
        for (int nt = 0; nt < 4; ++nt) acc[mt][nt] = (f32x4){0.f, 0.f, 0.f, 0.f};

    const half_t* wbase = wt2 + (size_t)(s * 9) * 2048;
#pragma unroll 1
    for (int tap = 0; tap < 9; ++tap) {
        int ky = tap / 3, kx = tap - ky * 3;
        half8 bfrag[4];
#pragma unroll
        for (int nt = 0; nt < 4; ++nt)
            bfrag[nt] = *(const half8*)(wbase + (size_t)tap * 2048 + (nt * 16 + l15) * 32 + g * 8);
#pragma unroll
        for (int mt = 0; mt < 4; ++mt) {
            int p = (wv * 4 + mt + ky) * 18 + l15 + kx;
            half8 afrag = *(const half8*)(smem + p * 80 + g * 16);
#pragma unroll
            for (int nt = 0; nt < 4; ++nt)
                acc[mt][nt] = __builtin_amdgcn_mfma_f32_16x16x32_f16(afrag, bfrag[nt], acc[mt][nt], 0, 0, 0);
        }
    }

    // bias + per-channel stats (wave shfl over g-groups, then LDS, then global)
    float s1a[4], s2a[4];
#pragma unroll
    for (int nt = 0; nt < 4; ++nt) {
        float bias = b2[s * 64 + nt * 16 + l15];
        float s1 = 0.f, s2 = 0.f;
#pragma unroll
        for (int mt = 0; mt < 4; ++mt)
#pragma unroll
            for (int r = 0; r < 4; ++r) {
                float v = acc[mt][nt][r] + bias;
                acc[mt][nt][r] = v;
                s1 += v; s2 += v * v;
            }
        s1 += __shfl_xor(s1, 16); s1 += __shfl_xor(s1, 32);
        s2 += __shfl_xor(s2, 16); s2 += __shfl_xor(s2, 32);
        s1a[nt] = s1; s2a[nt] = s2;
    }
    if (l < 16) {
#pragma unroll
        for (int nt = 0; nt < 4; ++nt) {
            atomicAdd(&statsl[(nt * 16 + l15) * 2], s1a[nt]);
            atomicAdd(&statsl[(nt * 16 + l15) * 2 + 1], s2a[nt]);
        }
    }
    __syncthreads();                      // stats done; input LDS free

    // bounce f16 tile [256 px][64 oc] then coalesced copy-out
#pragma unroll
    for (int mt = 0; mt < 4; ++mt)
#pragma unroll
        for (int nt = 0; nt < 4; ++nt)
#pragma unroll
            for (int r = 0; r < 4; ++r)
                out_lds[((wv * 4 + mt) * 16 + g * 4 + r) * 64 + nt * 16 + l15] = (half_t)acc[mt][nt][r];
    __syncthreads();

    const size_t base = (size_t)(n * NS + s) * NPIX * 64;
    for (int i = tid; i < 2048; i += 256) {
        int p = i >> 3, cc = i & 7;
        int gp = (ty * 16 + (p >> 4)) * 64 + tx * 16 + (p & 15);
        *(half8*)(h2 + base + (size_t)gp * 64 + cc * 8) = *(half8*)(smem + p * 128 + cc * 16);
    }
    if (tid < 128)
        atomicAdd(&sums2[(s * 64 + (tid >> 1)) * 2 + (tid & 1)], statsl[tid]);
}

// -------- conv3: 64->64 per seed, MFMA f16, BN2+ReLU folded in; writes pre-BN fp32 to d_out --------
__global__ __launch_bounds__(256) void conv3_k(
    const half_t* __restrict__ h2, const half_t* __restrict__ wt3,
    const float* __restrict__ b3, const float* __restrict__ a2,
    const float* __restrict__ b2p, float* __restrict__ out,
    float* __restrict__ sums3)
{
    __shared__ __align__(16) char smem[47680]; // in tile 324*144, pa/pb @46656, statsl @47168
    float* pa = (float*)(smem + 46656);
    float* pb = pa + 64;
    float* statsl = (float*)(smem + 47168);

    const int tile = blockIdx.x, s = blockIdx.y, n = blockIdx.z;
    const int tx = tile & 3, ty = tile >> 2, tid = threadIdx.x;

    if (tid < 64) { pa[tid] = a2[s * 64 + tid]; pb[tid] = b2p[s * 64 + tid]; }
    if (tid >= 128) statsl[tid - 128] = 0.f;
    __syncthreads();

    for (int i = tid; i < 2592; i += 256) {
        int p = i >> 3, cc = i & 7;
        int hy = p / 18, hx = p - hy * 18;
        int gy = ty * 16 + hy - 1, gx = tx * 16 + hx - 1;
        half8 v = {};
        if ((unsigned)gy < 64u && (unsigned)gx < 64u) {
            v = *(const half8*)(h2 + ((size_t)((n * NS + s) * NPIX + gy * 64 + gx)) * 64 + cc * 8);
#pragma unroll
            for (int j = 0; j < 8; ++j) {
                float f = fmaf(pa[cc * 8 + j], (float)v[j], pb[cc * 8 + j]);
                v[j] = (half_t)fmaxf(f, 0.f);
            }
        }
        *(half8*)(smem + p * 144 + cc * 16) = v;
    }
    __syncthreads();

    const int l = tid & 63, wv = tid >> 6, l15 = l & 15, g = l >> 4;
    f32x4 acc[4][4];
#pragma unroll
    for (int mt = 0; mt < 4; ++mt)
#pragma unroll
        for (int nt = 0; nt < 4; ++nt) acc[mt][nt] = (f32x4){0.f, 0.f, 0.f, 0.f};

    const half_t* wbase = wt3 + (size_t)(s * 9) * 4096;
#pragma unroll 1
    for (int tap = 0; tap < 9; ++tap) {
        int ky = tap / 3, kx = tap - ky * 3;
        half8 bfrag[4][2];
#pragma unroll
        for (int nt = 0; nt < 4; ++nt)
#pragma unroll
            for (int kc = 0; kc < 2; ++kc)
                bfrag[nt][kc] = *(const half8*)(wbase + (size_t)tap * 4096 + (nt * 16 + l15) * 64 + kc * 32 + g * 8);
#pragma unroll
        for (int mt = 0; mt < 4; ++mt) {
            int p = (wv * 4 + mt + ky) * 18 + l15 + kx;
            half8 af0 = *(const half8*)(smem + p * 144 + g * 16);
            half8 af1 = *(const half8*)(smem + p * 144 + 64 + g * 16);
#pragma unroll
            for (int nt = 0; nt < 4; ++nt) {
                acc[mt][nt] = __builtin_amdgcn_mfma_f32_16x16x32_f16(af0, bfrag[nt][0], acc[mt][nt], 0, 0, 0);
                acc[mt][nt] = __builtin_amdgcn_mfma_f32_16x16x32_f16(af1, bfrag[nt][1], acc[mt][nt], 0, 0, 0);
            }
        }
    }

    float s1a[4], s2a[4];
#pragma unroll
    for (int nt = 0; nt < 4; ++nt) {
        float bias = b3[s * 64 + nt * 16 + l15];
        float s1 = 0.f, s2 = 0.f;
#pragma unroll
        for (int mt = 0; mt < 4; ++mt)
#pragma unroll
            for (int r = 0; r < 4; ++r) {
                float v = acc[mt][nt][r] + bias;
                acc[mt][nt][r] = v;
                s1 += v; s2 += v * v;
            }
        s1 += __shfl_xor(s1, 16); s1 += __shfl_xor(s1, 32);
        s2 += __shfl_xor(s2, 16); s2 += __shfl_xor(s2, 32);
        s1a[nt] = s1; s2a[nt] = s2;
    }
    if (l < 16) {
#pragma unroll
        for (int nt = 0; nt < 4; ++nt) {
            atomicAdd(&statsl[(nt * 16 + l15) * 2], s1a[nt]);
            atomicAdd(&statsl[(nt * 16 + l15) * 2 + 1], s2a[nt]);
        }
    }

    // direct fp32 store into final layout out[s][n][c][y][x] (pre-BN3)
#pragma unroll
    for (int mt = 0; mt < 4; ++mt) {
        int gy = ty * 16 + wv * 4 + mt;
#pragma unroll
        for (int nt = 0; nt < 4; ++nt) {
            int c = nt * 16 + l15;
            *(f32x4*)(out + ((size_t)((s * NN + n) * 64 + c) * 64 + gy) * 64 + tx * 16 + g * 4) = acc[mt][nt];
        }
    }
    __syncthreads();
    if (tid < 128)
        atomicAdd(&sums3[(s * 64 + (tid >> 1)) * 2 + (tid & 1)], statsl[tid]);
}

// -------- final: in-place BN3+ReLU on d_out --------
__global__ __launch_bounds__(256) void final_k(float* __restrict__ out,
                                               const float* __restrict__ a3,
                                               const float* __restrict__ b3p)
{
    size_t i = ((size_t)blockIdx.x * 256 + threadIdx.x) * 4;
    int ch = (int)((i >> 12) & 63) + (int)(i >> 23) * 64; // c + s*64
    float sc = a3[ch], sh = b3p[ch];
    f32x4 v = *(f32x4*)(out + i);
#pragma unroll
    for (int r = 0; r < 4; ++r) v[r] = fmaxf(fmaf(sc, v[r], sh), 0.f);
    *(f32x4*)(out + i) = v;
}

extern "C" void kernel_launch(void* const* d_in, const int* in_sizes, int n_in,
                              void* d_out, int out_size, void* d_ws, size_t ws_size,
                              hipStream_t stream)
{
    const float* x   = (const float*)d_in[0];
    const float* w1  = (const float*)d_in[1];
    const float* b1  = (const float*)d_in[2];
    const float* g1  = (const float*)d_in[3];
    const float* be1 = (const float*)d_in[4];
    const float* w2  = (const float*)d_in[5];
    const float* b2  = (const float*)d_in[6];
    const float* g2  = (const float*)d_in[7];
    const float* be2 = (const float*)d_in[8];
    const float* w3  = (const float*)d_in[9];
    const float* b3  = (const float*)d_in[10];
    const float* g3  = (const float*)d_in[11];
    const float* be3 = (const float*)d_in[12];

    char* ws = (char*)d_ws;
    half_t* h1 = (half_t*)(ws + OFF_H1);
    half_t* h2 = (half_t*)(ws + OFF_H2);
    float* wt1 = (float*)(ws + OFF_WT1);
    half_t* wt2 = (half_t*)(ws + OFF_WT2);
    half_t* wt3 = (half_t*)(ws + OFF_WT3);
    float* sums = (float*)(ws + OFF_SUMS);
    float* s1v = sums, *s2v = sums + 1024, *s3v = sums + 3072;
    float* prm = (float*)(ws + OFF_PRM);
    float *a1 = prm, *b1p = prm + 512, *a2 = prm + 1024, *b2p = prm + 2048;
    float *a3 = prm + 3072, *b3p = prm + 4096;
    float* out = (float*)d_out;

    hipMemsetAsync(ws + OFF_SUMS, 0, 20480, stream);
    transform_k<<<3510, 256, 0, stream>>>(w1, w2, w3, wt1, wt2, wt3);
    dim3 grid(16, 16, 32); // (tile, seed, sample)
    conv1_k<<<grid, 256, 0, stream>>>(x, wt1, b1, h1, s1v);
    bnparam_k<<<2, 256, 0, stream>>>(s1v, g1, be1, a1, b1p, 512);
    conv2_k<<<grid, 256, 0, stream>>>(h1, wt2, b2, a1, b1p, h2, s2v);
    bnparam_k<<<4, 256, 0, stream>>>(s2v, g2, be2, a2, b2p, 1024);
    conv3_k<<<grid, 256, 0, stream>>>(h2, wt3, b3, a2, b2p, out, s3v);
    bnparam_k<<<4, 256, 0, stream>>>(s3v, g3, be3, a3, b3p, 1024);
    final_k<<<131072, 256, 0, stream>>>(out, a3, b3p);
}